// Round 7
// baseline (4105.270 us; speedup 1.0000x reference)
//
#include <hip/hip_runtime.h>
#include <hip/hip_bf16.h>

#define THREADS 512
#define NWAVE (THREADS / 64)

typedef unsigned long long ull;

// f32 max with DPP-shifted partner; old=self so masked lanes are no-ops.
// GCNDPPCombine folds the dpp-mov into v_max_f32 (single instruction).
template<int CTRL, int RM>
__device__ __forceinline__ float fmax_dpp(float v) {
    int s = __builtin_amdgcn_update_dpp(__float_as_int(v), __float_as_int(v),
                                        CTRL, RM, 0xf, false);
    return fmaxf(v, __int_as_float(s));
}

// u64 (value,~idx) key max via DPP (round-5 validated).
template<int CTRL, int RM>
__device__ __forceinline__ ull kmax_dpp(ull k) {
    unsigned hi = (unsigned)(k >> 32), lo = (unsigned)k;
    unsigned hi2 = (unsigned)__builtin_amdgcn_update_dpp((int)hi, (int)hi, CTRL, RM, 0xf, false);
    unsigned lo2 = (unsigned)__builtin_amdgcn_update_dpp((int)lo, (int)lo, CTRL, RM, 0xf, false);
    ull k2 = ((ull)hi2 << 32) | lo2;
    return (k2 > k) ? k2 : k;
}

// One block per cloud, 8 waves (2/SIMD). 512-thread block means only 2
// waves/SIMD must be co-resident -> __launch_bounds__(512,2) raises the
// arch-VGPR cap to 256, so the full NPT=40 state (160 floats) lives in
// architectural VGPRs with NO AGPR copy traffic (the round-2..6 killer:
// 1024-thread blocks force 4 waves/SIMD -> 128-reg cap -> 64/64 split).
//
// Per iteration (ONE barrier):
//  1. dist pass, value-only max (10 VALU/pt, 4 accumulators)
//  2. wave f32 max: 6 DPP rounds -> readlane(63) -> smax in SGPR
//  3. index recovery on the SCALAR pipe: NPT ballots (1 VALU each) ->
//     first nonzero mask via SALU selects -> ctzll. Exact: fmax returns
//     one of its inputs bit-exactly; j ascending & lane ascending =
//     smallest global index (np.argmax first-occurrence).
//  4. leader packs (maxbits<<32)|~idx, writes LDS partial (parity dbuf);
//     barrier; 8-partial u64 row-DPP max; readlane(7) -> winner idx;
//     uniform scalar load of winner coords (L2-resident).
template<int NPT>
__global__ __launch_bounds__(THREADS, 2)
void fps_kernel(const float* __restrict__ C, int n_pts, int m,
                int* __restrict__ idx_out) {
    const int b = blockIdx.x;
    const int t = threadIdx.x;
    const float* __restrict__ P = C + (size_t)b * n_pts * 3;

    float px[NPT], py[NPT], pz[NPT], dist[NPT];
#pragma unroll
    for (int j = 0; j < NPT; ++j) {
        int g = t + j * THREADS;
        if (g < n_pts) {
            px[j] = P[3 * g + 0];
            py[j] = P[3 * g + 1];
            pz[j] = P[3 * g + 2];
            dist[j] = 1e10f;
        } else {
            px[j] = 0.f; py[j] = 0.f; pz[j] = 0.f;
            dist[j] = -1.0f;   // sentinel: never equals smax (>= 0)
        }
    }

    __shared__ ull s_p[2][NWAVE];

    if (t == 0) idx_out[(size_t)b * m] = 0;   // first index is always 0

    // initial center = point 0 (uniform -> scalar load)
    float lx = P[0], ly = P[1], lz = P[2];

    const int wid = t >> 6;

    for (int it = 1; it < m; ++it) {
        const int par = it & 1;

        // 1. distance + min update, value-only max (4 accumulators)
        float vm0 = -2.0f, vm1 = -2.0f, vm2 = -2.0f, vm3 = -2.0f;
#pragma unroll
        for (int j = 0; j < NPT; ++j) {
            float dx = __fsub_rn(px[j], lx);
            float dy = __fsub_rn(py[j], ly);
            float dz = __fsub_rn(pz[j], lz);
            float d  = __fadd_rn(__fadd_rn(__fmul_rn(dx, dx), __fmul_rn(dy, dy)),
                                 __fmul_rn(dz, dz));
            float nd = fminf(dist[j], d);
            dist[j] = nd;
            switch (j & 3) {
                case 0: vm0 = fmaxf(vm0, nd); break;
                case 1: vm1 = fmaxf(vm1, nd); break;
                case 2: vm2 = fmaxf(vm2, nd); break;
                default: vm3 = fmaxf(vm3, nd); break;
            }
        }
        float v = fmaxf(fmaxf(vm0, vm1), fmaxf(vm2, vm3));

        // 2. wave max (value only), single-instr DPP rounds
        v = fmax_dpp<0x111, 0xf>(v);   // row_shr:1
        v = fmax_dpp<0x112, 0xf>(v);   // row_shr:2
        v = fmax_dpp<0x114, 0xf>(v);   // row_shr:4
        v = fmax_dpp<0x118, 0xf>(v);   // row_shr:8
        v = fmax_dpp<0x142, 0xa>(v);   // row_bcast:15 -> rows 1,3
        v = fmax_dpp<0x143, 0xc>(v);   // row_bcast:31 -> rows 2,3
        float smax = __int_as_float(
            __builtin_amdgcn_readlane(__float_as_int(v), 63));  // SGPR

        // 3. wave argmax index: ballots + scalar scan (SALU pipe)
        ull bestmask = 0;
        int bj = 0;
#pragma unroll
        for (int j = 0; j < NPT; ++j) {
            ull mj = __ballot(dist[j] == smax);
            bool take = (bestmask == 0);   // uniform -> scalar select
            if (take) { bestmask = mj; bj = j; }
        }
        int lane = (int)__builtin_ctzll(bestmask);
        int widx = wid * 64 + lane + bj * THREADS;

        // 4. pack key, leader writes partial, barrier, cross-wave reduce
        ull key = ((ull)__float_as_uint(smax) << 32) | (unsigned)(~widx);
        if ((t & 63) == 0) s_p[par][wid] = key;
        __syncthreads();

        ull kk = s_p[par][t & (NWAVE - 1)];
        kk = kmax_dpp<0x111, 0xf>(kk);       // row_shr:1
        kk = kmax_dpp<0x112, 0xf>(kk);       // row_shr:2
        kk = kmax_dpp<0x114, 0xf>(kk);       // row_shr:4 -> lane7 = total
        int sbi = ~__builtin_amdgcn_readlane((int)(unsigned)kk, 7);

        if (t == 0) idx_out[(size_t)b * m + it] = sbi;
        // winner coords: uniform (scalar) global load, L2-resident
        const float* __restrict__ wp = P + 3 * (size_t)(unsigned)sbi;
        lx = wp[0]; ly = wp[1]; lz = wp[2];
    }
}

// Gather sampled_C [batch,m,3] and sampled_F [batch,m,c] from the indices.
__global__ void gather_kernel(const float* __restrict__ C,
                              const float* __restrict__ F,
                              const int* __restrict__ idx,
                              float* __restrict__ outC,
                              float* __restrict__ outF,
                              int n_pts, int m, int c) {
    int pair = blockIdx.x;            // b*m + s
    int b = pair / m;
    int src = idx[pair];
    size_t srcbase = (size_t)b * n_pts + src;
    const float* sF = F + srcbase * (size_t)c;
    float* dF = outF + (size_t)pair * c;
    for (int i = threadIdx.x; i < c; i += blockDim.x) dF[i] = sF[i];
    if (threadIdx.x < 3)
        outC[(size_t)pair * 3 + threadIdx.x] = C[srcbase * 3 + threadIdx.x];
}

extern "C" void kernel_launch(void* const* d_in, const int* in_sizes, int n_in,
                              void* d_out, int out_size, void* d_ws, size_t ws_size,
                              hipStream_t stream) {
    const float* C = (const float*)d_in[0];
    const float* F = (const float*)d_in[1];

    int n_total = in_sizes[0] / 3;          // batch * n_pts
    int c       = in_sizes[1] / n_total;    // feature dim (128)
    int bm      = out_size / (3 + c);       // batch * m

    int batch = 8;
    if (bm % 2000 == 0) {
        int bb = bm / 2000;
        if (bb > 0 && n_total % bb == 0 && n_total / bb >= 2000) batch = bb;
    }
    int n_pts = n_total / batch;
    int m     = (n_pts < 2000) ? n_pts : 2000;

    int* idxbuf = (int*)d_ws;               // batch*m ints
    float* outC = (float*)d_out;
    float* outF = outC + (size_t)batch * m * 3;

    int npt = (n_pts + THREADS - 1) / THREADS;
#define LAUNCH_FPS(N) fps_kernel<N><<<batch, THREADS, 0, stream>>>(C, n_pts, m, idxbuf)
    if      (npt <= 8)  LAUNCH_FPS(8);
    else if (npt <= 16) LAUNCH_FPS(16);
    else if (npt <= 24) LAUNCH_FPS(24);
    else if (npt <= 32) LAUNCH_FPS(32);
    else if (npt <= 40) LAUNCH_FPS(40);
    else                LAUNCH_FPS(48);
#undef LAUNCH_FPS

    gather_kernel<<<batch * m, 128, 0, stream>>>(C, F, idxbuf, outC, outF,
                                                 n_pts, m, c);
}

// Round 8
// 3971.253 us; speedup vs baseline: 1.0337x; 1.0337x over previous
//
#include <hip/hip_runtime.h>
#include <hip/hip_bf16.h>

typedef unsigned long long ull;

#define THREADS 1024
#define NWAVE 16

// ---------------- DPP wave-reduce helpers (rounds 5-7 validated) ----------
template<int CTRL, int RM>
__device__ __forceinline__ float fmax_dpp(float v) {
    int s = __builtin_amdgcn_update_dpp(__float_as_int(v), __float_as_int(v), CTRL, RM, 0xf, false);
    return fmaxf(v, __int_as_float(s));
}
template<int CTRL, int RM>
__device__ __forceinline__ float fmin_dpp(float v) {
    int s = __builtin_amdgcn_update_dpp(__float_as_int(v), __float_as_int(v), CTRL, RM, 0xf, false);
    return fminf(v, __int_as_float(s));
}
template<int CTRL, int RM>
__device__ __forceinline__ float fadd_dpp(float v) {
    int s = __builtin_amdgcn_update_dpp(0, __float_as_int(v), CTRL, RM, 0xf, false);
    return v + __int_as_float(s);
}
template<int CTRL, int RM>
__device__ __forceinline__ ull kmax_dpp(ull k) {
    unsigned hi = (unsigned)(k >> 32), lo = (unsigned)k;
    unsigned hi2 = (unsigned)__builtin_amdgcn_update_dpp((int)hi, (int)hi, CTRL, RM, 0xf, false);
    unsigned lo2 = (unsigned)__builtin_amdgcn_update_dpp((int)lo, (int)lo, CTRL, RM, 0xf, false);
    ull k2 = ((ull)hi2 << 32) | lo2;
    return (k2 > k) ? k2 : k;
}
__device__ __forceinline__ float wave_fmax(float v) {
    v = fmax_dpp<0x111,0xf>(v); v = fmax_dpp<0x112,0xf>(v);
    v = fmax_dpp<0x114,0xf>(v); v = fmax_dpp<0x118,0xf>(v);
    v = fmax_dpp<0x142,0xa>(v); v = fmax_dpp<0x143,0xc>(v);
    return v;                       // total in lane 63
}
__device__ __forceinline__ float wave_fmin(float v) {
    v = fmin_dpp<0x111,0xf>(v); v = fmin_dpp<0x112,0xf>(v);
    v = fmin_dpp<0x114,0xf>(v); v = fmin_dpp<0x118,0xf>(v);
    v = fmin_dpp<0x142,0xa>(v); v = fmin_dpp<0x143,0xc>(v);
    return v;
}
__device__ __forceinline__ float wave_fsum(float v) {
    v = fadd_dpp<0x111,0xf>(v); v = fadd_dpp<0x112,0xf>(v);
    v = fadd_dpp<0x114,0xf>(v); v = fadd_dpp<0x118,0xf>(v);
    v = fadd_dpp<0x142,0xa>(v); v = fadd_dpp<0x143,0xc>(v);
    return v;
}
__device__ __forceinline__ ull wave_kmax(ull k) {
    k = kmax_dpp<0x111,0xf>(k); k = kmax_dpp<0x112,0xf>(k);
    k = kmax_dpp<0x114,0xf>(k); k = kmax_dpp<0x118,0xf>(k);
    k = kmax_dpp<0x142,0xa>(k); k = kmax_dpp<0x143,0xc>(k);
    return k;
}
__device__ __forceinline__ float bc63(float v) {
    return __int_as_float(__builtin_amdgcn_readlane(__float_as_int(v), 63));
}
__device__ __forceinline__ int morton4(int x, int y, int z) {
    int r = 0;
#pragma unroll
    for (int k = 0; k < 4; ++k)
        r |= ((x >> k & 1) << (3 * k)) | ((y >> k & 1) << (3 * k + 1)) | ((z >> k & 1) << (3 * k + 2));
    return r;
}
__device__ __forceinline__ int cellof(float x, float y, float z,
                                      float bx, float by, float bz,
                                      float ivx, float ivy, float ivz) {
    int ix = (int)((x - bx) * ivx); ix = ix < 0 ? 0 : (ix > 15 ? 15 : ix);
    int iy = (int)((y - by) * ivy); iy = iy < 0 ? 0 : (iy > 15 ? 15 : iy);
    int iz = (int)((z - bz) * ivz); iz = iz < 0 ? 0 : (iz > 15 ? 15 : iz);
    return morton4(ix, iy, iz);
}

// Exact grouped lazy-prune FPS. One block per cloud (n <= 32767).
// Preproc: bbox -> 16^3 Morton cells -> LDS counting sort -> groups of 64
// sorted points; per group bounding sphere (q,r). Sorted (x,y,z,orig) in
// global scratch; dist[] + group keys/meta in dynamic LDS.
// Per iteration: (A) bound test per group -> update list (pruning is
// conservative: a skipped group provably has min_p d(p,c) >= max_p dist_p,
// so no dist changes -- exactness never depends on the bound). (C) updated
// groups: one wave-task each, exact __f*_rn distance, LDS dist update,
// wave argmax with min-ORIG tie-break. (D) block argmax over group keys
// (distbits<<32 | ~orig<<15 | pos) -> winner coords via uniform load.
__global__ __launch_bounds__(THREADS)
void fps_grouped(const float* __restrict__ C, float4* __restrict__ gxyzo,
                 int n, int m, int GP, int G, int* __restrict__ idx_out) {
    const int b = blockIdx.x;
    const int t = threadIdx.x;
    const int lane = t & 63;
    const int wid  = t >> 6;
    const float* __restrict__ P = C + (size_t)b * n * 3;
    float4* __restrict__ gx = gxyzo + (size_t)b * GP;

    extern __shared__ char smem[];
    float4* s_meta = (float4*)smem;                               // G
    ull*    s_gkey = (ull*)(smem + 16 * G);                       // 1024
    ull*    s_part = s_gkey + 1024;                               // 2*16
    int*    s_misc = (int*)(s_part + 32);                        // 32 ints ([0]=cnt,[8..23] scan)
    float*  s_red  = (float*)(s_misc + 32);                      // 96 floats
    unsigned short* s_list = (unsigned short*)(s_red + 96);      // 1024
    int distofs = ((16 * G + 11008) + 15) & ~15;
    float*  s_dist = (float*)(smem + distofs);                   // GP floats
    unsigned* s_hist = (unsigned*)s_dist;                        // 4096 alias (preproc only)
    int distbytes = GP * 4; if (distbytes < 16384) distbytes = 16384;
    unsigned short* s_orig = (unsigned short*)(smem + distofs + distbytes); // GP

    // ---- P1: bbox ----
    float mnx = 1e30f, mny = 1e30f, mnz = 1e30f;
    float mxx = -1e30f, mxy = -1e30f, mxz = -1e30f;
    for (int g = t; g < n; g += THREADS) {
        float x = P[3 * g], y = P[3 * g + 1], z = P[3 * g + 2];
        mnx = fminf(mnx, x); mxx = fmaxf(mxx, x);
        mny = fminf(mny, y); mxy = fmaxf(mxy, y);
        mnz = fminf(mnz, z); mxz = fmaxf(mxz, z);
    }
    mnx = wave_fmin(mnx); mny = wave_fmin(mny); mnz = wave_fmin(mnz);
    mxx = wave_fmax(mxx); mxy = wave_fmax(mxy); mxz = wave_fmax(mxz);
    if (lane == 63) {
        s_red[wid * 6 + 0] = mnx; s_red[wid * 6 + 1] = mny; s_red[wid * 6 + 2] = mnz;
        s_red[wid * 6 + 3] = mxx; s_red[wid * 6 + 4] = mxy; s_red[wid * 6 + 5] = mxz;
    }
    __syncthreads();
    if (t == 0) {
        float a0 = 1e30f, a1 = 1e30f, a2 = 1e30f, b0 = -1e30f, b1 = -1e30f, b2 = -1e30f;
        for (int w = 0; w < NWAVE; ++w) {
            a0 = fminf(a0, s_red[w * 6 + 0]); a1 = fminf(a1, s_red[w * 6 + 1]);
            a2 = fminf(a2, s_red[w * 6 + 2]); b0 = fmaxf(b0, s_red[w * 6 + 3]);
            b1 = fmaxf(b1, s_red[w * 6 + 4]); b2 = fmaxf(b2, s_red[w * 6 + 5]);
        }
        s_red[0] = a0; s_red[1] = a1; s_red[2] = a2;
        s_red[3] = 15.9999f / (b0 - a0 + 1e-20f);
        s_red[4] = 15.9999f / (b1 - a1 + 1e-20f);
        s_red[5] = 15.9999f / (b2 - a2 + 1e-20f);
    }
    __syncthreads();
    const float bx = s_red[0], by = s_red[1], bz = s_red[2];
    const float ivx = s_red[3], ivy = s_red[4], ivz = s_red[5];

    // ---- P2: histogram ----
    for (int i = t; i < 4096; i += THREADS) s_hist[i] = 0;
    __syncthreads();
    for (int g = t; g < n; g += THREADS) {
        float x = P[3 * g], y = P[3 * g + 1], z = P[3 * g + 2];
        atomicAdd(&s_hist[cellof(x, y, z, bx, by, bz, ivx, ivy, ivz)], 1u);
    }
    __syncthreads();

    // ---- P3: exclusive scan over 4096 cells ----
    {
        unsigned c0 = s_hist[4 * t], c1 = s_hist[4 * t + 1];
        unsigned c2 = s_hist[4 * t + 2], c3 = s_hist[4 * t + 3];
        unsigned sum4 = c0 + c1 + c2 + c3;
        unsigned incl = sum4;
        for (int off = 1; off < 64; off <<= 1) {
            unsigned u = (unsigned)__shfl_up((int)incl, off);
            if (lane >= off) incl += u;
        }
        if (lane == 63) s_misc[8 + wid] = (int)incl;
        __syncthreads();
        unsigned woff = 0;
        for (int w = 0; w < wid; ++w) woff += (unsigned)s_misc[8 + w];
        unsigned base = woff + incl - sum4;
        s_hist[4 * t]     = base;
        s_hist[4 * t + 1] = base + c0;
        s_hist[4 * t + 2] = base + c0 + c1;
        s_hist[4 * t + 3] = base + c0 + c1 + c2;
    }
    __syncthreads();

    // ---- P4: scatter (sorted coords + orig idx) ----
    for (int g = t; g < n; g += THREADS) {
        float x = P[3 * g], y = P[3 * g + 1], z = P[3 * g + 2];
        unsigned pos = atomicAdd(&s_hist[cellof(x, y, z, bx, by, bz, ivx, ivy, ivz)], 1u);
        gx[pos] = make_float4(x, y, z, (float)g);
        s_orig[pos] = (unsigned short)g;
    }
    __syncthreads();

    // ---- P5: group metadata + init ----
    for (int g = wid; g < G; g += NWAVE) {
        int base = g * 64;
        int cnt64 = n - base; if (cnt64 > 64) cnt64 = 64;
        bool memb = lane < cnt64;
        int so = memb ? (int)s_orig[base + lane] : 0;
        float x = 0.f, y = 0.f, z = 0.f;
        if (memb) { x = P[3 * so]; y = P[3 * so + 1]; z = P[3 * so + 2]; }
        float qx = bc63(wave_fsum(x)) / (float)cnt64;
        float qy = bc63(wave_fsum(y)) / (float)cnt64;
        float qz = bc63(wave_fsum(z)) / (float)cnt64;
        float ex = x - qx, ey = y - qy, ez = z - qz;
        float e2 = memb ? (ex * ex + ey * ey + ez * ez) : 0.0f;
        float r = sqrtf(bc63(wave_fmax(e2))) * 1.0001f + 1e-6f;
        if (lane == 0) {
            s_meta[g] = make_float4(qx, qy, qz, r);
            s_gkey[g] = ((ull)__float_as_uint(1e10f) << 32) | 1ULL;  // force iter-1 update
        }
        s_dist[base + lane] = memb ? 1e10f : -1.0f;
        if (!memb) gx[base + lane] = make_float4(qx, qy, qz, 32767.0f);
    }
    if (t >= G) s_gkey[t] = 0;
    if (t == 0) { s_misc[0] = 0; idx_out[(size_t)b * m] = 0; }
    __threadfence();
    __syncthreads();

    // ---- main loop ----
    float lx = P[0], ly = P[1], lz = P[2];
    const size_t iobase = (size_t)b * m;
    for (int it = 1; it < m; ++it) {
        const int par = (it & 1) * 16;
        // Phase A: prune test + build update list
        if (t < G) {
            float4 mt = s_meta[t];
            float gmax = __uint_as_float((unsigned)(s_gkey[t] >> 32));
            float ax = lx - mt.x, ay = ly - mt.y, az = lz - mt.z;
            float lb = sqrtf(ax * ax + ay * ay + az * az) - mt.w;
            bool upd = true;
            if (lb > 0.0f) upd = (lb * lb * 0.9999f - 1e-6f) < gmax;
            if (upd) { int p = atomicAdd(&s_misc[0], 1); s_list[p] = (unsigned short)t; }
        }
        __syncthreads();                       // (1)
        const int U = s_misc[0];
        // Phase C: update flagged groups (one wave-task per group)
        for (int li = wid; li < U; li += NWAVE) {
            int g = (int)s_list[li];
            int gp = g * 64 + lane;
            float4 w = gx[gp];
            float dcur = s_dist[gp];
            float dx = __fsub_rn(w.x, lx);
            float dy = __fsub_rn(w.y, ly);
            float dz = __fsub_rn(w.z, lz);
            float d  = __fadd_rn(__fadd_rn(__fmul_rn(dx, dx), __fmul_rn(dy, dy)),
                                 __fmul_rn(dz, dz));
            float nd = fminf(dcur, d);
            s_dist[gp] = nd;
            int orig = (int)w.w;
            float vmax = bc63(wave_fmax(nd));
            ull mask = __ballot(nd == vmax);   // pads (nd=-1) never match; >=1 member matches
            int bl = (int)__builtin_ctzll(mask);
            int worig = __builtin_amdgcn_readlane(orig, bl);
            mask &= mask - 1;
            while (mask) {                     // rare exact ties: min ORIGINAL index
                int l2 = (int)__builtin_ctzll(mask);
                int o2 = __builtin_amdgcn_readlane(orig, l2);
                if (o2 < worig) { worig = o2; bl = l2; }
                mask &= mask - 1;
            }
            if (lane == 63)
                s_gkey[g] = ((ull)__float_as_uint(vmax) << 32)
                          | ((ull)(unsigned)((0x7fff - worig) << 15))
                          | (ull)(unsigned)(g * 64 + bl);
        }
        __syncthreads();                       // (2)
        // Phase D: block argmax over group keys
        ull kk = wave_kmax(s_gkey[t]);
        if (lane == 63) s_part[par + wid] = kk;
        if (t == 0) s_misc[0] = 0;             // safe: nobody touches cnt until after (3)
        __syncthreads();                       // (3)
        ull k2 = s_part[par + (t & 15)];
        k2 = kmax_dpp<0x111,0xf>(k2);
        k2 = kmax_dpp<0x112,0xf>(k2);
        k2 = kmax_dpp<0x114,0xf>(k2);
        k2 = kmax_dpp<0x118,0xf>(k2);          // lane 15 of each row = total
        unsigned lo = (unsigned)__builtin_amdgcn_readlane((int)(unsigned)k2, 15);
        int pos  = (int)(lo & 0x7fffu);
        int orig = 0x7fff - (int)((lo >> 15) & 0x7fffu);
        if (t == 0) idx_out[iobase + it] = orig;
        float4 wn = gx[pos];                   // uniform -> scalar load, L2-resident
        lx = wn.x; ly = wn.y; lz = wn.z;
    }
}

// Fallback for n > 32767 (never hit for this problem shape): simple exact
// brute force, dist in global scratch.
__global__ __launch_bounds__(1024)
void fps_brute(const float* __restrict__ C, float* __restrict__ gdist,
               int n, int m, int* __restrict__ idx_out) {
    const int b = blockIdx.x, t = threadIdx.x;
    const int lane = t & 63, wid = t >> 6;
    const float* __restrict__ P = C + (size_t)b * n * 3;
    float* __restrict__ dist = gdist + (size_t)b * n;
    __shared__ ull sp[2][16];
    for (int g = t; g < n; g += 1024) dist[g] = 1e10f;
    if (t == 0) idx_out[(size_t)b * m] = 0;
    float lx = P[0], ly = P[1], lz = P[2];
    __syncthreads();
    for (int it = 1; it < m; ++it) {
        int par = it & 1;
        ull k = 0;
        for (int g = t; g < n; g += 1024) {
            float dx = __fsub_rn(P[3 * g], lx);
            float dy = __fsub_rn(P[3 * g + 1], ly);
            float dz = __fsub_rn(P[3 * g + 2], lz);
            float d = __fadd_rn(__fadd_rn(__fmul_rn(dx, dx), __fmul_rn(dy, dy)),
                                __fmul_rn(dz, dz));
            float nd = fminf(dist[g], d);
            dist[g] = nd;
            ull kk = ((ull)__float_as_uint(nd) << 32) | (unsigned)(~g);
            if (kk > k) k = kk;
        }
        for (int off = 1; off < 64; off <<= 1) {
            ull ok = __shfl_xor(k, off);
            if (ok > k) k = ok;
        }
        if (lane == 0) sp[par][wid] = k;
        __syncthreads();
        ull kmaxv = sp[par][0];
        for (int w = 1; w < 16; ++w) { ull v = sp[par][w]; if (v > kmaxv) kmaxv = v; }
        int sbi = (int)~(unsigned)kmaxv;
        if (t == 0) idx_out[(size_t)b * m + it] = sbi;
        const float* wp = P + 3 * (size_t)(unsigned)sbi;
        lx = wp[0]; ly = wp[1]; lz = wp[2];
    }
}

__global__ void gather_kernel(const float* __restrict__ C,
                              const float* __restrict__ F,
                              const int* __restrict__ idx,
                              float* __restrict__ outC,
                              float* __restrict__ outF,
                              int n_pts, int m, int c) {
    int pair = blockIdx.x;            // b*m + s
    int b = pair / m;
    int src = idx[pair];
    size_t srcbase = (size_t)b * n_pts + src;
    const float* sF = F + srcbase * (size_t)c;
    float* dF = outF + (size_t)pair * c;
    for (int i = threadIdx.x; i < c; i += blockDim.x) dF[i] = sF[i];
    if (threadIdx.x < 3)
        outC[(size_t)pair * 3 + threadIdx.x] = C[srcbase * 3 + threadIdx.x];
}

extern "C" void kernel_launch(void* const* d_in, const int* in_sizes, int n_in,
                              void* d_out, int out_size, void* d_ws, size_t ws_size,
                              hipStream_t stream) {
    const float* C = (const float*)d_in[0];
    const float* F = (const float*)d_in[1];

    int n_total = in_sizes[0] / 3;
    int c       = in_sizes[1] / n_total;
    int bm      = out_size / (3 + c);

    int batch = 8;
    if (bm % 2000 == 0) {
        int bb = bm / 2000;
        if (bb > 0 && n_total % bb == 0 && n_total / bb >= 2000) batch = bb;
    }
    int n_pts = n_total / batch;
    int m     = (n_pts < 2000) ? n_pts : 2000;

    int* idxbuf = (int*)d_ws;
    float* outC = (float*)d_out;
    float* outF = outC + (size_t)batch * m * 3;

    int G  = (n_pts + 63) >> 6;
    int GP = G << 6;
    size_t idxbytes = (((size_t)batch * m * 4) + 255) & ~(size_t)255;
    size_t scrbytes = (size_t)batch * GP * 16;
    void* scratch;
    if (ws_size >= idxbytes + scrbytes)
        scratch = (char*)d_ws + idxbytes;
    else
        scratch = (char*)d_out + ((((size_t)out_size * 4) - scrbytes) & ~(size_t)15);

    if (n_pts <= 32767) {
        int distbytes = GP * 4; if (distbytes < 16384) distbytes = 16384;
        int distofs = ((16 * G + 11008) + 15) & ~15;
        size_t smem = (size_t)distofs + distbytes + (size_t)GP * 2 + 64;
        hipFuncSetAttribute((const void*)fps_grouped,
                            hipFuncAttributeMaxDynamicSharedMemorySize, (int)smem);
        fps_grouped<<<batch, THREADS, smem, stream>>>(C, (float4*)scratch,
                                                      n_pts, m, GP, G, idxbuf);
    } else {
        fps_brute<<<batch, 1024, 0, stream>>>(C, (float*)scratch, n_pts, m, idxbuf);
    }

    gather_kernel<<<batch * m, 128, 0, stream>>>(C, F, idxbuf, outC, outF,
                                                 n_pts, m, c);
}